// Round 3
// baseline (359.878 us; speedup 1.0000x reference)
//
#include <hip/hip_runtime.h>
#include <cstddef>

#define EPS_ 1e-6f

typedef unsigned short u16;
typedef __attribute__((ext_vector_type(8))) short short8;      // bf16x8 MFMA frag
typedef __attribute__((ext_vector_type(8))) unsigned short us8;
typedef __attribute__((ext_vector_type(4))) unsigned short us4;
typedef __attribute__((ext_vector_type(4))) float f32x4;

__device__ __forceinline__ float sigmoidf_(float x){ return 1.0f/(1.0f+__expf(-x)); }
__device__ __forceinline__ u16 f2bf(float x){
  union { float f; unsigned i; } c; c.f = x;
  unsigned r = c.i + 0x7FFFu + ((c.i >> 16) & 1u);   // RNE
  return (u16)(r >> 16);
}
__device__ __forceinline__ float bf2f(u16 u){
  union { unsigned i; float f; } c; c.i = ((unsigned)u) << 16; return c.f;
}

// ---------------------------------------------------------------------------
// WT[e][d] = bf16(W[d][e])
// ---------------------------------------------------------------------------
__global__ __launch_bounds__(256) void prep_w(const float* __restrict__ Wq,
                                              const float* __restrict__ Wk,
                                              u16* __restrict__ WqT,
                                              u16* __restrict__ WkT){
  const int e = blockIdx.x & 255;
  const float* W = (blockIdx.x < 256) ? Wq : Wk;
  u16* WT = (blockIdx.x < 256) ? WqT : WkT;
  const int d = threadIdx.x;
  WT[e*256 + d] = f2bf(W[d*256 + e]);
}

// ---------------------------------------------------------------------------
// phi GEMM v2: phi = sigmoid(X @ W + b). 128x128 tile, 4 waves (2x2), BK=32.
// A: f32->bf16 staged via double-buffered LDS w/ register prefetch (1 barrier/iter).
// B: fragments loaded DIRECTLY from WT global (L1/L2-hot, no LDS).
// Epilogues stage through the A-buffer union with vectorized, conflict-checked
// patterns. !TRANS: [row][f] + rowsum.  TRANS: [b][f][n] + colsum.
// ---------------------------------------------------------------------------
template<bool TRANS>
__global__ __launch_bounds__(256) void phi_gemm(const float* __restrict__ X,
    const u16* __restrict__ WT, const float* __restrict__ bias,
    u16* __restrict__ outp, float* __restrict__ sums)
{
  __shared__ union ShU {
    u16 A[2][128][40];   // K-loop staging (20480 B), stride 40 u16 -> even banks
    u16 S[128][72];      // !TRANS epilogue: [row][f-half 64]+pad
    u16 T[128][70];      // TRANS epilogue: [f][n-half 64]+pad
  } sh;

  const int t = threadIdx.x;
  const int l = t & 63;
  const int w = t >> 6;
  const int wm = w & 1, wf = w >> 1;
  const int f0   = blockIdx.x * 128;
  const int row0 = blockIdx.y * 128;
  const int i16 = l & 15, q = l >> 4;

  // A staging assignment: thread loads 4 float4 (rows sr+32p, k-off sk)
  const int sr = t >> 3;
  const int sk = (t & 7) * 4;

  float4 pre[4];
  #pragma unroll
  for (int p = 0; p < 4; p++)
    pre[p] = *(const float4*)&X[(size_t)(row0 + sr + 32*p) * 256 + sk];

  f32x4 acc[4][4];
  #pragma unroll
  for (int i=0;i<4;i++)
    #pragma unroll
    for (int j=0;j<4;j++) acc[i][j] = (f32x4){0.f,0.f,0.f,0.f};

  // stage pre -> LDS buf
  #pragma unroll
  for (int p = 0; p < 4; p++) {
    us4 h; h[0]=f2bf(pre[p].x); h[1]=f2bf(pre[p].y); h[2]=f2bf(pre[p].z); h[3]=f2bf(pre[p].w);
    *(us4*)&sh.A[0][sr + 32*p][sk] = h;
  }
  __syncthreads();

  const u16* wbase = WT + (size_t)(f0 + wf*64 + i16) * 256 + q*8;

  for (int it = 0; it < 8; it++) {
    if (it < 7) {
      const int k0n = (it+1) * 32;
      #pragma unroll
      for (int p = 0; p < 4; p++)
        pre[p] = *(const float4*)&X[(size_t)(row0 + sr + 32*p) * 256 + k0n + sk];
    }
    short8 bfr[4];
    #pragma unroll
    for (int fi=0;fi<4;fi++)
      bfr[fi] = *(const short8*)&wbase[fi*4096 + it*32];
    short8 af[4];
    #pragma unroll
    for (int mi=0;mi<4;mi++)
      af[mi] = *(const short8*)&sh.A[it & 1][wm*64 + mi*16 + i16][q*8];
    #pragma unroll
    for (int mi=0;mi<4;mi++)
      #pragma unroll
      for (int fi=0;fi<4;fi++)
        acc[mi][fi] = __builtin_amdgcn_mfma_f32_16x16x32_bf16(af[mi], bfr[fi], acc[mi][fi], 0,0,0);
    if (it < 7) {
      #pragma unroll
      for (int p = 0; p < 4; p++) {
        us4 h; h[0]=f2bf(pre[p].x); h[1]=f2bf(pre[p].y); h[2]=f2bf(pre[p].z); h[3]=f2bf(pre[p].w);
        *(us4*)&sh.A[(it+1)&1][sr + 32*p][sk] = h;
      }
    }
    __syncthreads();
  }

  float bv[4];
  #pragma unroll
  for (int fi=0;fi<4;fi++) bv[fi] = bias[f0 + wf*64 + fi*16 + i16];

  if (!TRANS) {
    // two f-half passes through sh.S; fused rowsum
    #pragma unroll
    for (int h = 0; h < 2; h++) {
      if (wf == h) {
        #pragma unroll
        for (int mi=0;mi<4;mi++) {
          float rsub[4] = {0.f,0.f,0.f,0.f};
          #pragma unroll
          for (int fi=0;fi<4;fi++) {
            #pragma unroll
            for (int r=0;r<4;r++) {
              float ph = sigmoidf_(acc[mi][fi][r] + bv[fi]);
              rsub[r] += ph;
              sh.S[wm*64 + mi*16 + q*4 + r][fi*16 + i16] = f2bf(ph);
            }
          }
          #pragma unroll
          for (int r=0;r<4;r++) {
            float s = rsub[r];
            s += __shfl_xor(s,1); s += __shfl_xor(s,2); s += __shfl_xor(s,4); s += __shfl_xor(s,8);
            if (i16 == 0) atomicAdd(&sums[row0 + wm*64 + mi*16 + q*4 + r], s);
          }
        }
      }
      __syncthreads();
      #pragma unroll
      for (int j=0;j<4;j++) {
        int idx = t + 256*j;
        int rr = idx >> 3, off = (idx & 7) * 8;
        *(us8*)&outp[(size_t)(row0 + rr)*256 + f0 + h*64 + off] = *(const us8*)&sh.S[rr][off];
      }
      __syncthreads();
    }
  } else {
    const int b = row0 >> 12;
    const int nbase = row0 & 4095;
    // two n-half passes through sh.T; fused colsum
    #pragma unroll
    for (int h = 0; h < 2; h++) {
      if (wm == h) {
        #pragma unroll
        for (int fi=0; fi<4; fi++) {
          float cp = 0.f;
          #pragma unroll
          for (int mi=0; mi<4; mi++) {
            us4 hv;
            #pragma unroll
            for (int r=0;r<4;r++){
              float ph = sigmoidf_(acc[mi][fi][r] + bv[fi]);
              cp += ph; hv[r] = f2bf(ph);
            }
            *(us4*)&sh.T[wf*64 + fi*16 + i16][mi*16 + q*4] = hv;
          }
          cp += __shfl_xor(cp,16); cp += __shfl_xor(cp,32);
          if (l < 16) atomicAdd(&sums[b*256 + f0 + wf*64 + fi*16 + i16], cp);
        }
      }
      __syncthreads();
      #pragma unroll
      for (int j=0;j<4;j++) {
        int idx = t + 256*j;
        int fr = idx >> 3, ch = (idx & 7) * 8;
        *(us8*)&outp[(size_t)(b*256 + f0 + fr)*4096 + nbase + h*64 + ch] = *(const us8*)&sh.T[fr][ch];
      }
      __syncthreads();
    }
  }
}

// ---------------------------------------------------------------------------
// KV partials v2: grid (e0/64, nc 0..15, b). Block: d=256 x e=64, 4 c-iters of 64 n.
// E[n,e] = exp(phi_k * inv_cs * V) (V direct-coalesced global; phiT reg-prefetch).
// parts[nc][b][d][e] = bf16 unnormalized partial; denom accumulated f32 atomics.
// ---------------------------------------------------------------------------
__global__ __launch_bounds__(256) void kv_kernel(const u16* __restrict__ phi_kT,
    const float* __restrict__ V, const float* __restrict__ colsum,
    u16* __restrict__ parts, float* __restrict__ denom)
{
  __shared__ u16 phiT_lds[256][72];   // [d][n 64], stride 144 B
  __shared__ u16 E_lds[64][72];       // [e][n 64]

  const int t = threadIdx.x;
  const int l = t & 63;
  const int w = t >> 6;
  const int e0 = blockIdx.x * 64;
  const int nc = blockIdx.y;
  const int b  = blockIdx.z;
  const int nbase = nc * 256;
  const int i16 = l & 15, q = l >> 4;

  const int sd = t >> 3;          // staging d-base
  const int sn = (t & 7) * 8;     // staging n-offset

  us8  rA[8];
  float rV[16];
  {
    #pragma unroll
    for (int p=0;p<8;p++)
      rA[p] = *(const us8*)&phi_kT[(size_t)(b*256 + sd + 32*p)*4096 + nbase + sn];
    #pragma unroll
    for (int j=0;j<16;j++)
      rV[j] = V[(size_t)(b*4096 + nbase + w*16 + j)*256 + e0 + l];
  }

  const float inv_cs = 1.0f / (colsum[b*256 + e0 + l] + EPS_);
  float dsum = 0.f;

  f32x4 acc[4][4];
  #pragma unroll
  for (int i=0;i<4;i++)
    #pragma unroll
    for (int j=0;j<4;j++) acc[i][j] = (f32x4){0.f,0.f,0.f,0.f};

  for (int c = 0; c < 4; c++) {
    #pragma unroll
    for (int p=0;p<8;p++) *(us8*)&phiT_lds[sd + 32*p][sn] = rA[p];
    __syncthreads();
    const int n0n = nbase + (c+1)*64;
    if (c < 3) {
      #pragma unroll
      for (int p=0;p<8;p++)
        rA[p] = *(const us8*)&phi_kT[(size_t)(b*256 + sd + 32*p)*4096 + n0n + sn];
    }
    // E-compute: thread owns (e = l, n = w*16 .. +15)
    us8 pv0 = *(const us8*)&phiT_lds[e0 + l][w*16];
    us8 pv1 = *(const us8*)&phiT_lds[e0 + l][w*16 + 8];
    us8 ev0, ev1;
    #pragma unroll
    for (int j=0;j<8;j++) {
      float ef = __expf(bf2f(pv0[j]) * inv_cs * rV[j]);
      dsum += ef; ev0[j] = f2bf(ef);
    }
    #pragma unroll
    for (int j=0;j<8;j++) {
      float ef = __expf(bf2f(pv1[j]) * inv_cs * rV[8+j]);
      dsum += ef; ev1[j] = f2bf(ef);
    }
    *(us8*)&E_lds[l][w*16]     = ev0;
    *(us8*)&E_lds[l][w*16 + 8] = ev1;
    if (c < 3) {
      #pragma unroll
      for (int j=0;j<16;j++)
        rV[j] = V[(size_t)(b*4096 + n0n + w*16 + j)*256 + e0 + l];
    }
    __syncthreads();
    #pragma unroll
    for (int kk=0;kk<2;kk++){
      const int ko = kk*32 + q*8;
      short8 af[4], bfr[4];
      #pragma unroll
      for (int mi=0;mi<4;mi++) af[mi]  = *(const short8*)&phiT_lds[w*64 + mi*16 + i16][ko];
      #pragma unroll
      for (int ei=0;ei<4;ei++) bfr[ei] = *(const short8*)&E_lds[ei*16 + i16][ko];
      #pragma unroll
      for (int mi=0;mi<4;mi++)
        #pragma unroll
        for (int ei=0;ei<4;ei++)
          acc[mi][ei] = __builtin_amdgcn_mfma_f32_16x16x32_bf16(af[mi], bfr[ei], acc[mi][ei],0,0,0);
    }
    __syncthreads();
  }

  atomicAdd(&denom[b*256 + e0 + l], dsum);

  u16* slice = parts + ((size_t)(nc*16 + b)) * 65536;
  #pragma unroll
  for (int mi=0;mi<4;mi++)
    #pragma unroll
    for (int ei=0;ei<4;ei++)
      #pragma unroll
      for (int r=0;r<4;r++)
        slice[(size_t)(w*64 + mi*16 + q*4 + r)*256 + e0 + ei*16 + i16] = f2bf(acc[mi][ei][r]);
}

// ---------------------------------------------------------------------------
// KV_nT[b][e][d] = bf16( (sum_nc parts[nc][b][d][e]) / denom[b][e] )
// ---------------------------------------------------------------------------
__global__ __launch_bounds__(256) void kv_norm(const u16* __restrict__ parts,
    const float* __restrict__ denom, u16* __restrict__ KV_nT)
{
  __shared__ float tile[64][65];
  const int t = threadIdx.x;
  const int d0 = blockIdx.x*64, e0 = blockIdx.y*64, b = blockIdx.z;
  const int i = t >> 4, jq = t & 15;
  #pragma unroll
  for (int p=0;p<4;p++){
    int dl = p*16 + i;
    float s0=0.f,s1=0.f,s2=0.f,s3=0.f;
    for (int nc=0;nc<16;nc++){
      us4 v = *(const us4*)&parts[(((size_t)(nc*16 + b))*256 + d0 + dl)*256 + e0 + jq*4];
      s0+=bf2f(v[0]); s1+=bf2f(v[1]); s2+=bf2f(v[2]); s3+=bf2f(v[3]);
    }
    tile[dl][jq*4+0]=s0; tile[dl][jq*4+1]=s1; tile[dl][jq*4+2]=s2; tile[dl][jq*4+3]=s3;
  }
  __syncthreads();
  const int el = t >> 4, dq = t & 15;
  #pragma unroll
  for (int p=0;p<4;p++){
    int e = p*16 + el;
    float dn = denom[b*256 + e0 + e];
    us4 o;
    #pragma unroll
    for (int r=0;r<4;r++) o[r] = f2bf(tile[dq*4+r][e] / dn);
    *(us4*)&KV_nT[((size_t)(b*256 + e0 + e))*256 + d0 + dq*4] = o;
  }
}

// ---------------------------------------------------------------------------
// out[b,n,e] = sigmoid(rs)/(rs+eps) * sum_d phi_q[n,d] * KV_n[d,e]
// 128x128 tile, double-buffered LDS + register prefetch (1 barrier/iter).
// ---------------------------------------------------------------------------
__global__ __launch_bounds__(256) void out_gemm(const u16* __restrict__ phi_q,
    const u16* __restrict__ KV_nT, const float* __restrict__ rowsum,
    float* __restrict__ outp)
{
  __shared__ u16 A_lds[2][128][40];
  __shared__ u16 B_lds[2][128][40];
  __shared__ float rs_lds[128];

  const int t = threadIdx.x;
  const int l = t & 63;
  const int w = t >> 6;
  const int wm = w & 1, we = w >> 1;
  const int e0 = blockIdx.x * 128;
  const int n0 = blockIdx.y * 128;
  const int b  = blockIdx.z;
  const int i16 = l & 15, q = l >> 4;

  if (t < 128) rs_lds[t] = rowsum[b*4096 + n0 + t];

  const int nr = t >> 2, q4 = (t & 3) * 8;
  us8 pA[2], pB[2];
  #pragma unroll
  for (int p=0;p<2;p++){
    pA[p] = *(const us8*)&phi_q[(size_t)(b*4096 + n0 + p*64 + nr)*256 + q4];
    pB[p] = *(const us8*)&KV_nT[(size_t)(b*256 + e0 + p*64 + nr)*256 + q4];
  }
  #pragma unroll
  for (int p=0;p<2;p++){
    *(us8*)&A_lds[0][p*64+nr][q4] = pA[p];
    *(us8*)&B_lds[0][p*64+nr][q4] = pB[p];
  }
  __syncthreads();

  f32x4 acc[4][4];
  #pragma unroll
  for (int i=0;i<4;i++)
    #pragma unroll
    for (int j=0;j<4;j++) acc[i][j] = (f32x4){0.f,0.f,0.f,0.f};

  for (int it=0; it<8; it++){
    if (it < 7) {
      const int k0n = (it+1)*32;
      #pragma unroll
      for (int p=0;p<2;p++){
        pA[p] = *(const us8*)&phi_q[(size_t)(b*4096 + n0 + p*64 + nr)*256 + k0n + q4];
        pB[p] = *(const us8*)&KV_nT[(size_t)(b*256 + e0 + p*64 + nr)*256 + k0n + q4];
      }
    }
    short8 af[4], bfr[4];
    #pragma unroll
    for (int mi=0;mi<4;mi++) af[mi]  = *(const short8*)&A_lds[it&1][wm*64+mi*16+i16][q*8];
    #pragma unroll
    for (int ei=0;ei<4;ei++) bfr[ei] = *(const short8*)&B_lds[it&1][we*64+ei*16+i16][q*8];
    #pragma unroll
    for (int mi=0;mi<4;mi++)
      #pragma unroll
      for (int ei=0;ei<4;ei++)
        acc[mi][ei] = __builtin_amdgcn_mfma_f32_16x16x32_bf16(af[mi], bfr[ei], acc[mi][ei],0,0,0);
    if (it < 7) {
      #pragma unroll
      for (int p=0;p<2;p++){
        *(us8*)&A_lds[(it+1)&1][p*64+nr][q4] = pA[p];
        *(us8*)&B_lds[(it+1)&1][p*64+nr][q4] = pB[p];
      }
    }
    __syncthreads();
  }

  #pragma unroll
  for (int mi=0;mi<4;mi++){
    #pragma unroll
    for (int r=0;r<4;r++){
      int nl = wm*64 + mi*16 + q*4 + r;
      float rs = rs_lds[nl];
      float gate = sigmoidf_(rs) / (rs + EPS_);
      #pragma unroll
      for (int ei=0;ei<4;ei++)
        outp[((size_t)(b*4096 + n0 + nl))*256 + e0 + we*64 + ei*16 + i16] = gate*acc[mi][ei][r];
    }
  }
}

extern "C" void kernel_launch(void* const* d_in, const int* in_sizes, int n_in,
                              void* d_out, int out_size, void* d_ws, size_t ws_size,
                              hipStream_t stream) {
  const float* Q  = (const float*)d_in[0];
  const float* K  = (const float*)d_in[1];
  const float* V  = (const float*)d_in[2];
  const float* Wq = (const float*)d_in[3];
  const float* bq = (const float*)d_in[4];
  const float* Wk = (const float*)d_in[5];
  const float* bk = (const float*)d_in[6];
  float* out = (float*)d_out;

  // workspace layout (~100 MB)
  u16* phi_q  = (u16*)d_ws;                 // 16,777,216 bf16 [b][n][d]
  u16* phi_kT = phi_q + 16777216;           // 16,777,216 bf16 [b][d][n]
  u16* WqT    = phi_kT + 16777216;          // 65,536
  u16* WkT    = WqT + 65536;                // 65,536
  float* colsum = (float*)(WkT + 65536);    // 4096
  float* denom  = colsum + 4096;            // 4096
  float* rowsum = denom + 4096;             // 65,536
  u16* parts  = (u16*)(rowsum + 65536);     // 16*16*65536 bf16 (33.5 MB)
  u16* KV_nT  = parts + 16777216;           // 1,048,576 bf16 [b][e][d]

  hipMemsetAsync(colsum, 0, (4096 + 4096 + 65536) * sizeof(float), stream);

  prep_w<<<dim3(512), 256, 0, stream>>>(Wq, Wk, WqT, WkT);
  phi_gemm<false><<<dim3(2, 512), 256, 0, stream>>>(Q, WqT, bq, phi_q, rowsum);
  phi_gemm<true ><<<dim3(2, 512), 256, 0, stream>>>(K, WkT, bk, phi_kT, colsum);
  kv_kernel<<<dim3(4, 16, 16), 256, 0, stream>>>(phi_kT, V, colsum, parts, denom);
  kv_norm<<<dim3(4, 4, 16), 256, 0, stream>>>(parts, denom, KV_nT);
  out_gemm<<<dim3(2, 32, 16), 256, 0, stream>>>(phi_q, KV_nT, rowsum, out);
}

// Round 4
// 319.101 us; speedup vs baseline: 1.1278x; 1.1278x over previous
//
#include <hip/hip_runtime.h>
#include <cstddef>

#define EPS_ 1e-6f

typedef unsigned short u16;
typedef __attribute__((ext_vector_type(8))) short short8;      // bf16x8 MFMA frag
typedef __attribute__((ext_vector_type(8))) unsigned short us8;
typedef __attribute__((ext_vector_type(4))) unsigned short us4;
typedef __attribute__((ext_vector_type(4))) float f32x4;

__device__ __forceinline__ float sigmoidf_(float x){ return 1.0f/(1.0f+__expf(-x)); }
__device__ __forceinline__ u16 f2bf(float x){
  union { float f; unsigned i; } c; c.f = x;
  unsigned r = c.i + 0x7FFFu + ((c.i >> 16) & 1u);   // RNE
  return (u16)(r >> 16);
}
__device__ __forceinline__ float bf2f(u16 u){
  union { unsigned i; float f; } c; c.i = ((unsigned)u) << 16; return c.f;
}

// ---------------------------------------------------------------------------
// WT[e][d] = bf16(W[d][e])
// ---------------------------------------------------------------------------
__global__ __launch_bounds__(256) void prep_w(const float* __restrict__ Wq,
                                              const float* __restrict__ Wk,
                                              u16* __restrict__ WqT,
                                              u16* __restrict__ WkT){
  const int e = blockIdx.x & 255;
  const float* W = (blockIdx.x < 256) ? Wq : Wk;
  u16* WT = (blockIdx.x < 256) ? WqT : WkT;
  const int d = threadIdx.x;
  WT[e*256 + d] = f2bf(W[d*256 + e]);
}

// ---------------------------------------------------------------------------
// phi_both: z=0: phi_q = sigmoid(Q@Wq+bq) -> [row][f] bf16 + rowsum (atomic)
//           z=1: phi_kT = sigmoid(K@Wk+bk)^T -> [b][f][n] bf16 + colsum (atomic)
// 512 threads = 8 waves (2 row-halves x 4 f-quarters), tile 128 rows x 256 f.
// X tile staged to LDS ONCE as bf16 (1 barrier); K-loop is pure ds_read+MFMA
// with B-frags streamed from L2-hot WT via 2-deep register ping-pong (nothing
// else in the vmcnt queue -> fine-grained waits actually overlap).
// ---------------------------------------------------------------------------
__global__ __launch_bounds__(512, 4) void phi_both(
    const float* __restrict__ Q, const float* __restrict__ K,
    const u16* __restrict__ WqT, const u16* __restrict__ WkT,
    const float* __restrict__ bq, const float* __restrict__ bk,
    u16* __restrict__ phi_q, u16* __restrict__ phi_kT,
    float* __restrict__ rowsum, float* __restrict__ colsum)
{
  __shared__ union {
    u16 A[128][264];   // [row][k], stride 528 B (16B mult); 67584 B
    u16 S[128][264];   // !trans epilogue [row][f]
    u16 T[256][136];   // trans epilogue [f][n], stride 272 B; 69632 B
  } sh;

  const int t = threadIdx.x;
  const int l = t & 63;
  const int w = t >> 6;
  const int wm = w & 1;       // row half (64)
  const int wf = w >> 1;      // f quarter (64)
  const int i16 = l & 15, q = l >> 4;
  const int row0 = blockIdx.x * 128;
  const bool trans = (blockIdx.z != 0);

  const float* X    = trans ? K   : Q;
  const u16*  WT    = trans ? WkT : WqT;
  const float* bias = trans ? bk  : bq;

  // ---- stage X tile (128x256 f32 -> bf16 LDS), one shot ----
  {
    const int r0 = t >> 4;         // 0..31
    const int c0 = t & 15;         // float4 col
    #pragma unroll
    for (int p2 = 0; p2 < 4; p2++) {
      #pragma unroll
      for (int p1 = 0; p1 < 4; p1++) {
        const int row = r0 + 32*p2;
        const int k4  = c0 + 16*p1;
        float4 v = *(const float4*)&X[(size_t)(row0 + row)*256 + k4*4];
        us4 h; h[0]=f2bf(v.x); h[1]=f2bf(v.y); h[2]=f2bf(v.z); h[3]=f2bf(v.w);
        *(us4*)&sh.A[row][k4*4] = h;
      }
    }
  }
  __syncthreads();

  // ---- K loop: 8 steps, no barriers ----
  f32x4 acc[4][4];
  #pragma unroll
  for (int i=0;i<4;i++)
    #pragma unroll
    for (int j=0;j<4;j++) acc[i][j] = (f32x4){0.f,0.f,0.f,0.f};

  const u16* wb = WT + (size_t)(wf*64 + i16)*256 + q*8;
  short8 Bfr[2][4];
  #pragma unroll
  for (int fi=0;fi<4;fi++) Bfr[0][fi] = *(const short8*)&wb[fi*4096];

  #pragma unroll
  for (int it = 0; it < 8; it++) {
    if (it < 7) {
      #pragma unroll
      for (int fi=0;fi<4;fi++)
        Bfr[(it+1)&1][fi] = *(const short8*)&wb[fi*4096 + (it+1)*32];
    }
    short8 af[4];
    #pragma unroll
    for (int mi=0;mi<4;mi++)
      af[mi] = *(const short8*)&sh.A[wm*64 + mi*16 + i16][it*32 + q*8];
    #pragma unroll
    for (int mi=0;mi<4;mi++)
      #pragma unroll
      for (int fi=0;fi<4;fi++)
        acc[mi][fi] = __builtin_amdgcn_mfma_f32_16x16x32_bf16(af[mi], Bfr[it&1][fi], acc[mi][fi], 0,0,0);
  }

  float bv[4];
  #pragma unroll
  for (int fi=0;fi<4;fi++) bv[fi] = bias[wf*64 + fi*16 + i16];

  __syncthreads();   // A-reads done; LDS is reusable

  if (!trans) {
    #pragma unroll
    for (int mi=0;mi<4;mi++) {
      float rs[4] = {0.f,0.f,0.f,0.f};
      #pragma unroll
      for (int fi=0;fi<4;fi++) {
        #pragma unroll
        for (int r=0;r<4;r++) {
          float ph = sigmoidf_(acc[mi][fi][r] + bv[fi]);
          rs[r] += ph;
          sh.S[wm*64 + mi*16 + q*4 + r][wf*64 + fi*16 + i16] = f2bf(ph);
        }
      }
      #pragma unroll
      for (int r=0;r<4;r++) {
        float s = rs[r];
        s += __shfl_xor(s,1); s += __shfl_xor(s,2); s += __shfl_xor(s,4); s += __shfl_xor(s,8);
        if (i16 == 0) atomicAdd(&rowsum[row0 + wm*64 + mi*16 + q*4 + r], s);
      }
    }
    __syncthreads();
    const int row = t >> 2;
    #pragma unroll
    for (int p=0;p<8;p++) {
      const int off = (t&3)*8 + p*32;
      *(us8*)&phi_q[(size_t)(row0 + row)*256 + off] = *(const us8*)&sh.S[row][off];
    }
  } else {
    const int b  = row0 >> 12;
    const int nb = row0 & 4095;
    #pragma unroll
    for (int fi=0;fi<4;fi++) {
      float cp = 0.f;
      #pragma unroll
      for (int mi=0;mi<4;mi++) {
        #pragma unroll
        for (int r=0;r<4;r++) {
          float ph = sigmoidf_(acc[mi][fi][r] + bv[fi]);
          cp += ph;
          sh.T[wf*64 + fi*16 + i16][wm*64 + mi*16 + q*4 + r] = f2bf(ph);
        }
      }
      cp += __shfl_xor(cp,16); cp += __shfl_xor(cp,32);   // reduce over q
      if (l < 16) atomicAdd(&colsum[b*256 + wf*64 + fi*16 + i16], cp);
    }
    __syncthreads();
    #pragma unroll
    for (int p2=0;p2<2;p2++) {
      const int f = (t >> 2) + 128*p2;
      #pragma unroll
      for (int p=0;p<4;p++) {
        const int off = (t&3)*8 + p*32;
        *(us8*)&phi_kT[(size_t)(b*256 + f)*4096 + nb + off] = *(const us8*)&sh.T[f][off];
      }
    }
  }
}

// ---------------------------------------------------------------------------
// KV partials: grid (e0/64, nc 0..15, b). Block: d=256 x e=64, 4 c-iters of 64 n.
// E[n,e] = exp(phi_k * inv_cs * V) (V direct-coalesced; phiT reg-prefetch).
// parts[nc][b][d][e] bf16 unnormalized; denom f32 atomics.
// ---------------------------------------------------------------------------
__global__ __launch_bounds__(256) void kv_kernel(const u16* __restrict__ phi_kT,
    const float* __restrict__ V, const float* __restrict__ colsum,
    u16* __restrict__ parts, float* __restrict__ denom)
{
  __shared__ u16 phiT_lds[256][72];   // [d][n 64]
  __shared__ u16 E_lds[64][72];       // [e][n 64]

  const int t = threadIdx.x;
  const int l = t & 63;
  const int w = t >> 6;
  const int e0 = blockIdx.x * 64;
  const int nc = blockIdx.y;
  const int b  = blockIdx.z;
  const int nbase = nc * 256;
  const int i16 = l & 15, q = l >> 4;

  const int sd = t >> 3;
  const int sn = (t & 7) * 8;

  us8  rA[8];
  float rV[16];
  #pragma unroll
  for (int p=0;p<8;p++)
    rA[p] = *(const us8*)&phi_kT[(size_t)(b*256 + sd + 32*p)*4096 + nbase + sn];
  #pragma unroll
  for (int j=0;j<16;j++)
    rV[j] = V[(size_t)(b*4096 + nbase + w*16 + j)*256 + e0 + l];

  const float inv_cs = 1.0f / (colsum[b*256 + e0 + l] + EPS_);
  float dsum = 0.f;

  f32x4 acc[4][4];
  #pragma unroll
  for (int i=0;i<4;i++)
    #pragma unroll
    for (int j=0;j<4;j++) acc[i][j] = (f32x4){0.f,0.f,0.f,0.f};

  for (int c = 0; c < 4; c++) {
    #pragma unroll
    for (int p=0;p<8;p++) *(us8*)&phiT_lds[sd + 32*p][sn] = rA[p];
    __syncthreads();
    const int n0n = nbase + (c+1)*64;
    if (c < 3) {
      #pragma unroll
      for (int p=0;p<8;p++)
        rA[p] = *(const us8*)&phi_kT[(size_t)(b*256 + sd + 32*p)*4096 + n0n + sn];
    }
    us8 pv0 = *(const us8*)&phiT_lds[e0 + l][w*16];
    us8 pv1 = *(const us8*)&phiT_lds[e0 + l][w*16 + 8];
    us8 ev0, ev1;
    #pragma unroll
    for (int j=0;j<8;j++) {
      float ef = __expf(bf2f(pv0[j]) * inv_cs * rV[j]);
      dsum += ef; ev0[j] = f2bf(ef);
    }
    #pragma unroll
    for (int j=0;j<8;j++) {
      float ef = __expf(bf2f(pv1[j]) * inv_cs * rV[8+j]);
      dsum += ef; ev1[j] = f2bf(ef);
    }
    *(us8*)&E_lds[l][w*16]     = ev0;
    *(us8*)&E_lds[l][w*16 + 8] = ev1;
    if (c < 3) {
      #pragma unroll
      for (int j=0;j<16;j++)
        rV[j] = V[(size_t)(b*4096 + n0n + w*16 + j)*256 + e0 + l];
    }
    __syncthreads();
    #pragma unroll
    for (int kk=0;kk<2;kk++){
      const int ko = kk*32 + q*8;
      short8 af[4], bfr[4];
      #pragma unroll
      for (int mi=0;mi<4;mi++) af[mi]  = *(const short8*)&phiT_lds[w*64 + mi*16 + i16][ko];
      #pragma unroll
      for (int ei=0;ei<4;ei++) bfr[ei] = *(const short8*)&E_lds[ei*16 + i16][ko];
      #pragma unroll
      for (int mi=0;mi<4;mi++)
        #pragma unroll
        for (int ei=0;ei<4;ei++)
          acc[mi][ei] = __builtin_amdgcn_mfma_f32_16x16x32_bf16(af[mi], bfr[ei], acc[mi][ei],0,0,0);
    }
    __syncthreads();
  }

  atomicAdd(&denom[b*256 + e0 + l], dsum);

  u16* slice = parts + ((size_t)(nc*16 + b)) * 65536;
  #pragma unroll
  for (int mi=0;mi<4;mi++)
    #pragma unroll
    for (int ei=0;ei<4;ei++)
      #pragma unroll
      for (int r=0;r<4;r++)
        slice[(size_t)(w*64 + mi*16 + q*4 + r)*256 + e0 + ei*16 + i16] = f2bf(acc[mi][ei][r]);
}

// ---------------------------------------------------------------------------
// KV_nT[b][e][d] = bf16( (sum_nc parts[nc][b][d][e]) / denom[b][e] )
// ---------------------------------------------------------------------------
__global__ __launch_bounds__(256) void kv_norm(const u16* __restrict__ parts,
    const float* __restrict__ denom, u16* __restrict__ KV_nT)
{
  __shared__ float tile[64][65];
  const int t = threadIdx.x;
  const int d0 = blockIdx.x*64, e0 = blockIdx.y*64, b = blockIdx.z;
  const int i = t >> 4, jq = t & 15;
  #pragma unroll
  for (int p=0;p<4;p++){
    int dl = p*16 + i;
    float s0=0.f,s1=0.f,s2=0.f,s3=0.f;
    for (int nc=0;nc<16;nc++){
      us4 v = *(const us4*)&parts[(((size_t)(nc*16 + b))*256 + d0 + dl)*256 + e0 + jq*4];
      s0+=bf2f(v[0]); s1+=bf2f(v[1]); s2+=bf2f(v[2]); s3+=bf2f(v[3]);
    }
    tile[dl][jq*4+0]=s0; tile[dl][jq*4+1]=s1; tile[dl][jq*4+2]=s2; tile[dl][jq*4+3]=s3;
  }
  __syncthreads();
  const int el = t >> 4, dq = t & 15;
  #pragma unroll
  for (int p=0;p<4;p++){
    int e = p*16 + el;
    float dn = denom[b*256 + e0 + e];
    us4 o;
    #pragma unroll
    for (int r=0;r<4;r++) o[r] = f2bf(tile[dq*4+r][e] / dn);
    *(us4*)&KV_nT[((size_t)(b*256 + e0 + e))*256 + d0 + dq*4] = o;
  }
}

// ---------------------------------------------------------------------------
// out[b,n,e] = sigmoid(rs)/(rs+eps) * sum_d phi_q[n,d] * KV_n[d,e]
// Same single-shot structure as phi_both: A=phi_q tile in LDS (1 barrier),
// B=KV_nT (128 KB/batch, L2-hot) streamed via register ping-pong.
// 512 threads, tile 128 n x 256 e.
// ---------------------------------------------------------------------------
__global__ __launch_bounds__(512, 4) void out_gemm(const u16* __restrict__ phi_q,
    const u16* __restrict__ KV_nT, const float* __restrict__ rowsum,
    float* __restrict__ outp)
{
  __shared__ u16 A_lds[128][264];
  __shared__ float rs_lds[128];

  const int t = threadIdx.x;
  const int l = t & 63;
  const int w = t >> 6;
  const int wm = w & 1, we = w >> 1;
  const int i16 = l & 15, q = l >> 4;
  const int n0 = blockIdx.x * 128;
  const int b  = blockIdx.y;

  if (t < 128) rs_lds[t] = rowsum[b*4096 + n0 + t];

  {
    const int row = t >> 2;
    #pragma unroll
    for (int p=0;p<8;p++) {
      const int off = (t&3)*8 + p*32;
      *(us8*)&A_lds[row][off] = *(const us8*)&phi_q[(size_t)(b*4096 + n0 + row)*256 + off];
    }
  }
  __syncthreads();

  f32x4 acc[4][4];
  #pragma unroll
  for (int i=0;i<4;i++)
    #pragma unroll
    for (int j=0;j<4;j++) acc[i][j] = (f32x4){0.f,0.f,0.f,0.f};

  const u16* kb = KV_nT + (size_t)(b*256 + we*64 + i16)*256 + q*8;
  short8 Bfr[2][4];
  #pragma unroll
  for (int ei=0;ei<4;ei++) Bfr[0][ei] = *(const short8*)&kb[ei*4096];

  #pragma unroll
  for (int it=0; it<8; it++){
    if (it < 7) {
      #pragma unroll
      for (int ei=0;ei<4;ei++)
        Bfr[(it+1)&1][ei] = *(const short8*)&kb[ei*4096 + (it+1)*32];
    }
    short8 af[4];
    #pragma unroll
    for (int mi=0;mi<4;mi++)
      af[mi] = *(const short8*)&A_lds[wm*64 + mi*16 + i16][it*32 + q*8];
    #pragma unroll
    for (int mi=0;mi<4;mi++)
      #pragma unroll
      for (int ei=0;ei<4;ei++)
        acc[mi][ei] = __builtin_amdgcn_mfma_f32_16x16x32_bf16(af[mi], Bfr[it&1][ei], acc[mi][ei],0,0,0);
  }

  #pragma unroll
  for (int mi=0;mi<4;mi++){
    #pragma unroll
    for (int r=0;r<4;r++){
      const int nl = wm*64 + mi*16 + q*4 + r;
      float rs = rs_lds[nl];
      float gate = sigmoidf_(rs) / (rs + EPS_);
      #pragma unroll
      for (int ei=0;ei<4;ei++)
        outp[((size_t)(b*4096 + n0 + nl))*256 + we*64 + ei*16 + i16] = gate*acc[mi][ei][r];
    }
  }
}

extern "C" void kernel_launch(void* const* d_in, const int* in_sizes, int n_in,
                              void* d_out, int out_size, void* d_ws, size_t ws_size,
                              hipStream_t stream) {
  const float* Q  = (const float*)d_in[0];
  const float* K  = (const float*)d_in[1];
  const float* V  = (const float*)d_in[2];
  const float* Wq = (const float*)d_in[3];
  const float* bq = (const float*)d_in[4];
  const float* Wk = (const float*)d_in[5];
  const float* bk = (const float*)d_in[6];
  float* out = (float*)d_out;

  u16* phi_q  = (u16*)d_ws;                 // 16,777,216 bf16 [b][n][d]
  u16* phi_kT = phi_q + 16777216;           // 16,777,216 bf16 [b][d][n]
  u16* WqT    = phi_kT + 16777216;          // 65,536
  u16* WkT    = WqT + 65536;                // 65,536
  float* colsum = (float*)(WkT + 65536);    // 4096
  float* denom  = colsum + 4096;            // 4096
  float* rowsum = denom + 4096;             // 65,536
  u16* parts  = (u16*)(rowsum + 65536);     // 16*16*65536 bf16 (33.5 MB)
  u16* KV_nT  = parts + 16777216;           // 1,048,576 bf16 [b][e][d]

  hipMemsetAsync(colsum, 0, (4096 + 4096 + 65536) * sizeof(float), stream);

  prep_w<<<dim3(512), 256, 0, stream>>>(Wq, Wk, WqT, WkT);
  phi_both<<<dim3(512, 1, 2), 512, 0, stream>>>(Q, K, WqT, WkT, bq, bk,
                                                phi_q, phi_kT, rowsum, colsum);
  kv_kernel<<<dim3(4, 16, 16), 256, 0, stream>>>(phi_kT, V, colsum, parts, denom);
  kv_norm<<<dim3(4, 4, 16), 256, 0, stream>>>(parts, denom, KV_nT);
  out_gemm<<<dim3(32, 16), 512, 0, stream>>>(phi_q, KV_nT, rowsum, out);
}

// Round 5
// 313.153 us; speedup vs baseline: 1.1492x; 1.0190x over previous
//
#include <hip/hip_runtime.h>
#include <cstddef>

#define EPS_ 1e-6f

typedef unsigned short u16;
typedef __attribute__((ext_vector_type(8))) short short8;      // bf16x8 MFMA frag
typedef __attribute__((ext_vector_type(8))) unsigned short us8;
typedef __attribute__((ext_vector_type(4))) unsigned short us4;
typedef __attribute__((ext_vector_type(4))) float f32x4;

__device__ __forceinline__ float sigmoidf_(float x){ return 1.0f/(1.0f+__expf(-x)); }
__device__ __forceinline__ u16 f2bf(float x){
  union { __bf16 b; u16 u; } c; c.b = (__bf16)x; return c.u;   // RNE, hw cvt if avail
}
__device__ __forceinline__ float bf2f(u16 u){
  union { unsigned i; float f; } c; c.i = ((unsigned)u) << 16; return c.f;
}
__device__ __forceinline__ us4 cvt4(float4 v){
  us4 h; h[0]=f2bf(v.x); h[1]=f2bf(v.y); h[2]=f2bf(v.z); h[3]=f2bf(v.w); return h;
}

// ---------------------------------------------------------------------------
// WT[e][d] = bf16(W[d][e])
// ---------------------------------------------------------------------------
__global__ __launch_bounds__(256) void prep_w(const float* __restrict__ Wq,
                                              const float* __restrict__ Wk,
                                              u16* __restrict__ WqT,
                                              u16* __restrict__ WkT){
  const int e = blockIdx.x & 255;
  const float* W = (blockIdx.x < 256) ? Wq : Wk;
  u16* WT = (blockIdx.x < 256) ? WqT : WkT;
  const int d = threadIdx.x;
  WT[e*256 + d] = f2bf(W[d*256 + e]);
}

// ---------------------------------------------------------------------------
// phi_both v3: z=0: phi_q = sigmoid(Q@Wq+bq) -> [row][f] bf16 + rowsum (atomic)
//              z=1: phi_kT = sigmoid(K@Wk+bk)^T -> TILED [b][nchunk][f][n64] + colsum
// 256 threads = 4 waves (f-quarters), tile 64 rows x 256 f. LDS ~34 KB ->
// 4 blocks/CU. X tile staged once (1 barrier); K-loop = ds_read + MFMA with
// W frags streamed from L2-hot WT via 2-deep register ping-pong.
// ---------------------------------------------------------------------------
__global__ __launch_bounds__(256, 4) void phi_both(
    const float* __restrict__ Q, const float* __restrict__ K,
    const u16* __restrict__ WqT, const u16* __restrict__ WkT,
    const float* __restrict__ bq, const float* __restrict__ bk,
    u16* __restrict__ phi_q, u16* __restrict__ phi_kT,
    float* __restrict__ rowsum, float* __restrict__ colsum)
{
  __shared__ union {
    u16 A[64][264];     // [row][k] staging, 33792 B (row 528 B = 16B mult)
    u16 S[64][264];     // !trans epilogue [row][f]
    u16 T2[128][136];   // trans epilogue half-pass [f&127][n], 34816 B
  } sh;

  const int t = threadIdx.x;
  const int l = t & 63;
  const int wf = t >> 6;          // f-quarter
  const int i16 = l & 15, q = l >> 4;
  const int row0 = blockIdx.x * 64;
  const bool trans = (blockIdx.z != 0);

  const float* X    = trans ? K   : Q;
  const u16*  WT    = trans ? WkT : WqT;
  const float* bias = trans ? bk  : bq;

  // ---- stage X tile (64x256 f32 -> bf16 LDS), one shot ----
  {
    const int r0 = t >> 4;        // 0..15
    const int c0 = t & 15;        // float4 col
    #pragma unroll
    for (int p2 = 0; p2 < 4; p2++) {
      #pragma unroll
      for (int p1 = 0; p1 < 4; p1++) {
        const int row = r0 + 16*p2;
        const int k4  = c0 + 16*p1;
        float4 v = *(const float4*)&X[(size_t)(row0 + row)*256 + k4*4];
        *(us4*)&sh.A[row][k4*4] = cvt4(v);
      }
    }
  }
  __syncthreads();

  // ---- K loop: 8 steps, no barriers ----
  f32x4 acc[4][4];
  #pragma unroll
  for (int i=0;i<4;i++)
    #pragma unroll
    for (int j=0;j<4;j++) acc[i][j] = (f32x4){0.f,0.f,0.f,0.f};

  const u16* wb = WT + (size_t)(wf*64 + i16)*256 + q*8;
  short8 Bfr[2][4];
  #pragma unroll
  for (int fi=0;fi<4;fi++) Bfr[0][fi] = *(const short8*)&wb[fi*4096];

  #pragma unroll
  for (int it = 0; it < 8; it++) {
    if (it < 7) {
      #pragma unroll
      for (int fi=0;fi<4;fi++)
        Bfr[(it+1)&1][fi] = *(const short8*)&wb[fi*4096 + (it+1)*32];
    }
    short8 af[4];
    #pragma unroll
    for (int mi=0;mi<4;mi++)
      af[mi] = *(const short8*)&sh.A[mi*16 + i16][it*32 + q*8];
    #pragma unroll
    for (int mi=0;mi<4;mi++)
      #pragma unroll
      for (int fi=0;fi<4;fi++)
        acc[mi][fi] = __builtin_amdgcn_mfma_f32_16x16x32_bf16(af[mi], Bfr[it&1][fi], acc[mi][fi], 0,0,0);
  }

  float bv[4];
  #pragma unroll
  for (int fi=0;fi<4;fi++) bv[fi] = bias[wf*64 + fi*16 + i16];

  __syncthreads();   // A reads done; LDS reusable

  if (!trans) {
    #pragma unroll
    for (int mi=0;mi<4;mi++) {
      float rsub[4] = {0.f,0.f,0.f,0.f};
      #pragma unroll
      for (int fi=0;fi<4;fi++) {
        #pragma unroll
        for (int r=0;r<4;r++) {
          float ph = sigmoidf_(acc[mi][fi][r] + bv[fi]);
          rsub[r] += ph;
          sh.S[mi*16 + q*4 + r][wf*64 + fi*16 + i16] = f2bf(ph);
        }
      }
      #pragma unroll
      for (int r=0;r<4;r++) {
        float s = rsub[r];
        s += __shfl_xor(s,1); s += __shfl_xor(s,2); s += __shfl_xor(s,4); s += __shfl_xor(s,8);
        if (i16 == 0) atomicAdd(&rowsum[row0 + mi*16 + q*4 + r], s);
      }
    }
    __syncthreads();
    const size_t gbase = (size_t)row0 * 256;
    #pragma unroll
    for (int j=0;j<8;j++) {
      const int g = (j*256 + t) * 8;       // u16 index in 16384
      *(us8*)&phi_q[gbase + g] = *(const us8*)&sh.S[g >> 8][g & 255];
    }
  } else {
    const int b      = row0 >> 12;
    const int nchunk = (row0 & 4095) >> 6;
    #pragma unroll
    for (int h = 0; h < 2; h++) {
      if ((wf >> 1) == h) {
        #pragma unroll
        for (int fi=0;fi<4;fi++) {
          float cp = 0.f;
          #pragma unroll
          for (int mi=0;mi<4;mi++) {
            #pragma unroll
            for (int r=0;r<4;r++) {
              float ph = sigmoidf_(acc[mi][fi][r] + bv[fi]);
              cp += ph;
              sh.T2[(wf*64 + fi*16 + i16) & 127][mi*16 + q*4 + r] = f2bf(ph);
            }
          }
          cp += __shfl_xor(cp,16); cp += __shfl_xor(cp,32);   // reduce over q
          if (l < 16) atomicAdd(&colsum[b*256 + wf*64 + fi*16 + l], cp);
        }
      }
      __syncthreads();
      // contiguous 16 KB tile store: [f 128][n 64] u16
      const size_t gb = ((size_t)(b*64 + nchunk)*256 + h*128) * 64;
      #pragma unroll
      for (int j=0;j<4;j++) {
        const int g = (j*256 + t) * 8;     // u16 index in 8192
        *(us8*)&phi_kT[gb + g] = *(const us8*)&sh.T2[g >> 6][g & 63];
      }
      __syncthreads();
    }
  }
}

// ---------------------------------------------------------------------------
// KV partials: grid (e0/64, nc 0..15, b). Block: d=256 x e=64, 4 chunks of 64 n.
// phi_kT is tiled [b][nchunk][d][n64] -> perfectly contiguous 32 KB chunk reads.
// E[n,e] = exp(phi_k*inv_cs*V); partsT[nc][b][e][d] bf16 (us4-packed along d);
// denom f32 atomics.
// ---------------------------------------------------------------------------
__global__ __launch_bounds__(256) void kv_kernel(const u16* __restrict__ phi_kT,
    const float* __restrict__ V, const float* __restrict__ colsum,
    u16* __restrict__ partsT, float* __restrict__ denom)
{
  __shared__ u16 phiT_lds[256][72];   // [d][n 64]
  __shared__ u16 E_lds[64][72];       // [e][n 64]

  const int t = threadIdx.x;
  const int l = t & 63;
  const int w = t >> 6;
  const int e0 = blockIdx.x * 64;
  const int nc = blockIdx.y;
  const int b  = blockIdx.z;
  const int i16 = l & 15, q = l >> 4;

  const int sd = t >> 3;          // staging d-base (0..31)
  const int sn = (t & 7) * 8;     // staging n-offset

  const size_t cbase = (size_t)(b*64 + nc*4) * 256 * 64;   // u16 idx of chunk 0

  us8  rA[8];
  float rV[16];
  #pragma unroll
  for (int p=0;p<8;p++)
    rA[p] = *(const us8*)&phi_kT[cbase + (size_t)(sd + 32*p)*64 + sn];
  #pragma unroll
  for (int j=0;j<16;j++)
    rV[j] = V[(size_t)(b*4096 + nc*256 + w*16 + j)*256 + e0 + l];

  const float inv_cs = 1.0f / (colsum[b*256 + e0 + l] + EPS_);
  float dsum = 0.f;

  f32x4 acc[4][4];
  #pragma unroll
  for (int i=0;i<4;i++)
    #pragma unroll
    for (int j=0;j<4;j++) acc[i][j] = (f32x4){0.f,0.f,0.f,0.f};

  for (int c = 0; c < 4; c++) {
    #pragma unroll
    for (int p=0;p<8;p++) *(us8*)&phiT_lds[sd + 32*p][sn] = rA[p];
    __syncthreads();
    if (c < 3) {
      const size_t nb = cbase + (size_t)(c+1)*16384;
      #pragma unroll
      for (int p=0;p<8;p++)
        rA[p] = *(const us8*)&phi_kT[nb + (size_t)(sd + 32*p)*64 + sn];
    }
    us8 pv0 = *(const us8*)&phiT_lds[e0 + l][w*16];
    us8 pv1 = *(const us8*)&phiT_lds[e0 + l][w*16 + 8];
    us8 ev0, ev1;
    #pragma unroll
    for (int j=0;j<8;j++) {
      float ef = __expf(bf2f(pv0[j]) * inv_cs * rV[j]);
      dsum += ef; ev0[j] = f2bf(ef);
    }
    #pragma unroll
    for (int j=0;j<8;j++) {
      float ef = __expf(bf2f(pv1[j]) * inv_cs * rV[8+j]);
      dsum += ef; ev1[j] = f2bf(ef);
    }
    *(us8*)&E_lds[l][w*16]     = ev0;
    *(us8*)&E_lds[l][w*16 + 8] = ev1;
    if (c < 3) {
      #pragma unroll
      for (int j=0;j<16;j++)
        rV[j] = V[(size_t)(b*4096 + nc*256 + (c+1)*64 + w*16 + j)*256 + e0 + l];
    }
    __syncthreads();
    #pragma unroll
    for (int kk=0;kk<2;kk++){
      const int ko = kk*32 + q*8;
      short8 af[4], bfr[4];
      #pragma unroll
      for (int mi=0;mi<4;mi++) af[mi]  = *(const short8*)&phiT_lds[w*64 + mi*16 + i16][ko];
      #pragma unroll
      for (int ei=0;ei<4;ei++) bfr[ei] = *(const short8*)&E_lds[ei*16 + i16][ko];
      #pragma unroll
      for (int mi=0;mi<4;mi++)
        #pragma unroll
        for (int ei=0;ei<4;ei++)
          acc[mi][ei] = __builtin_amdgcn_mfma_f32_16x16x32_bf16(af[mi], bfr[ei], acc[mi][ei],0,0,0);
    }
    __syncthreads();
  }

  atomicAdd(&denom[b*256 + e0 + l], dsum);

  // partsT[nc][b][e][d]: acc D-layout row=d=q*4+r (r contiguous) -> us4 along d
  u16* slice = partsT + (size_t)(nc*16 + b) * 65536;
  #pragma unroll
  for (int mi=0;mi<4;mi++)
    #pragma unroll
    for (int ei=0;ei<4;ei++) {
      us4 o;
      #pragma unroll
      for (int r=0;r<4;r++) o[r] = f2bf(acc[mi][ei][r]);
      *(us4*)&slice[(size_t)(e0 + ei*16 + i16)*256 + w*64 + mi*16 + q*4] = o;
    }
}

// ---------------------------------------------------------------------------
// KV_nT[b][e][d] = bf16( (sum_nc partsT[nc][b][e][d]) / denom[b][e] )
// Pure streaming: no LDS, us4 vector loads, 4 e-rows per block.
// ---------------------------------------------------------------------------
__global__ __launch_bounds__(256) void kv_norm(const u16* __restrict__ partsT,
    const float* __restrict__ denom, u16* __restrict__ KV_nT)
{
  const int t = threadIdx.x;
  const int b = blockIdx.y;
  const size_t idx = (size_t)blockIdx.x * 1024 + t*4;   // u16 index in [e][d] plane
  const int e = (int)(idx >> 8);
  const float dn = denom[b*256 + e];
  float s0=0.f,s1=0.f,s2=0.f,s3=0.f;
  #pragma unroll 4
  for (int nc=0;nc<16;nc++){
    us4 v = *(const us4*)&partsT[(size_t)(nc*16 + b)*65536 + idx];
    s0+=bf2f(v[0]); s1+=bf2f(v[1]); s2+=bf2f(v[2]); s3+=bf2f(v[3]);
  }
  us4 o; o[0]=f2bf(s0/dn); o[1]=f2bf(s1/dn); o[2]=f2bf(s2/dn); o[3]=f2bf(s3/dn);
  *(us4*)&KV_nT[(size_t)b*65536 + idx] = o;
}

// ---------------------------------------------------------------------------
// out[b,n,e] = sigmoid(rs)/(rs+eps) * sum_d phi_q[n,d] * KV_n[d,e]
// 64n x 256e tile, 256 threads (4 e-quarter waves), single-shot A in LDS,
// B = KV_nT (128 KB/batch, L2-hot) streamed via register ping-pong.
// ---------------------------------------------------------------------------
__global__ __launch_bounds__(256, 4) void out_gemm(const u16* __restrict__ phi_q,
    const u16* __restrict__ KV_nT, const float* __restrict__ rowsum,
    float* __restrict__ outp)
{
  __shared__ u16 A_lds[64][264];
  __shared__ float rs_lds[64];

  const int t = threadIdx.x;
  const int l = t & 63;
  const int we = t >> 6;
  const int i16 = l & 15, q = l >> 4;
  const int n0 = blockIdx.x * 64;
  const int b  = blockIdx.y;

  if (t < 64) rs_lds[t] = rowsum[b*4096 + n0 + t];

  {
    const size_t gbase = (size_t)(b*4096 + n0) * 256;
    #pragma unroll
    for (int j=0;j<8;j++) {
      const int g = (j*256 + t) * 8;
      *(us8*)&A_lds[g >> 8][g & 255] = *(const us8*)&phi_q[gbase + g];
    }
  }
  __syncthreads();

  f32x4 acc[4][4];
  #pragma unroll
  for (int i=0;i<4;i++)
    #pragma unroll
    for (int j=0;j<4;j++) acc[i][j] = (f32x4){0.f,0.f,0.f,0.f};

  const u16* kb = KV_nT + (size_t)(b*256 + we*64 + i16)*256 + q*8;
  short8 Bfr[2][4];
  #pragma unroll
  for (int ei=0;ei<4;ei++) Bfr[0][ei] = *(const short8*)&kb[ei*4096];

  #pragma unroll
  for (int it=0; it<8; it++){
    if (it < 7) {
      #pragma unroll
      for (int ei=0;ei<4;ei++)
        Bfr[(it+1)&1][ei] = *(const short8*)&kb[ei*4096 + (it+1)*32];
    }
    short8 af[4];
    #pragma unroll
    for (int mi=0;mi<4;mi++)
      af[mi] = *(const short8*)&A_lds[mi*16 + i16][it*32 + q*8];
    #pragma unroll
    for (int mi=0;mi<4;mi++)
      #pragma unroll
      for (int ei=0;ei<4;ei++)
        acc[mi][ei] = __builtin_amdgcn_mfma_f32_16x16x32_bf16(af[mi], Bfr[it&1][ei], acc[mi][ei],0,0,0);
  }

  #pragma unroll
  for (int mi=0;mi<4;mi++){
    #pragma unroll
    for (int r=0;r<4;r++){
      const int nl = mi*16 + q*4 + r;
      const float rs = rs_lds[nl];
      const float gate = sigmoidf_(rs) / (rs + EPS_);
      #pragma unroll
      for (int ei=0;ei<4;ei++)
        outp[((size_t)(b*4096 + n0 + nl))*256 + we*64 + ei*16 + i16] = gate*acc[mi][ei][r];
    }
  }
}

extern "C" void kernel_launch(void* const* d_in, const int* in_sizes, int n_in,
                              void* d_out, int out_size, void* d_ws, size_t ws_size,
                              hipStream_t stream) {
  const float* Q  = (const float*)d_in[0];
  const float* K  = (const float*)d_in[1];
  const float* V  = (const float*)d_in[2];
  const float* Wq = (const float*)d_in[3];
  const float* bq = (const float*)d_in[4];
  const float* Wk = (const float*)d_in[5];
  const float* bk = (const float*)d_in[6];
  float* out = (float*)d_out;

  u16* phi_q  = (u16*)d_ws;                 // 16,777,216 bf16 [b][n][d]
  u16* phi_kT = phi_q + 16777216;           // 16,777,216 bf16 TILED [b][nchunk][d][n64]
  u16* WqT    = phi_kT + 16777216;          // 65,536
  u16* WkT    = WqT + 65536;                // 65,536
  float* colsum = (float*)(WkT + 65536);    // 4096
  float* denom  = colsum + 4096;            // 4096
  float* rowsum = denom + 4096;             // 65,536
  u16* partsT = (u16*)(rowsum + 65536);     // 16*16*65536 bf16 (33.5 MB) [nc][b][e][d]
  u16* KV_nT  = partsT + 16777216;          // 1,048,576 bf16 [b][e][d]

  hipMemsetAsync(colsum, 0, (4096 + 4096 + 65536) * sizeof(float), stream);

  prep_w<<<dim3(512), 256, 0, stream>>>(Wq, Wk, WqT, WkT);
  phi_both<<<dim3(1024, 1, 2), 256, 0, stream>>>(Q, K, WqT, WkT, bq, bk,
                                                 phi_q, phi_kT, rowsum, colsum);
  kv_kernel<<<dim3(4, 16, 16), 256, 0, stream>>>(phi_kT, V, colsum, partsT, denom);
  kv_norm<<<dim3(64, 16), 256, 0, stream>>>(partsT, denom, KV_nT);
  out_gemm<<<dim3(64, 16), 256, 0, stream>>>(phi_q, KV_nT, rowsum, out);
}